// Round 15
// baseline (546.555 us; speedup 1.0000x reference)
//
#include <hip/hip_runtime.h>
#include <hip/hip_bf16.h>

#define VOCAB 50000
#define DD 256
#define NCLS 10
#define BB 64
#define SS 512
#define HH 512
#define K3D 768

typedef __attribute__((ext_vector_type(8))) short bf16x8;
typedef __attribute__((ext_vector_type(8))) unsigned short ush8;
typedef __attribute__((ext_vector_type(4))) float f32x4;

static __device__ __forceinline__ unsigned short f2bf(float f) {
    __hip_bfloat16 h = __float2bfloat16(f);
    return *reinterpret_cast<unsigned short*>(&h);
}

// 8x fp32 -> 8x bf16 via v_cvt_pk_bf16_f32 (RNE, low<-src0).
static __device__ __forceinline__ ush8 cvt8(const float* src) {
    const float4 lo = *(const float4*)(src);
    const float4 hi = *(const float4*)(src + 4);
    uint4 u;
    asm("v_cvt_pk_bf16_f32 %0, %1, %2" : "=v"(u.x) : "v"(lo.x), "v"(lo.y));
    asm("v_cvt_pk_bf16_f32 %0, %1, %2" : "=v"(u.y) : "v"(lo.z), "v"(lo.w));
    asm("v_cvt_pk_bf16_f32 %0, %1, %2" : "=v"(u.z) : "v"(hi.x), "v"(hi.y));
    asm("v_cvt_pk_bf16_f32 %0, %1, %2" : "=v"(u.w) : "v"(hi.z), "v"(hi.w));
    return *reinterpret_cast<ush8*>(&u);
}

// ---------------------------------------------------------------------------
// Kernel 1: small prep — convwb conversion + zero pooled + zero flags.
// ---------------------------------------------------------------------------
__global__ __launch_bounds__(256) void prep_small_kernel(
    const float* __restrict__ conv_w,
    unsigned short* __restrict__ convwb,
    float* __restrict__ pooled,
    int* __restrict__ cnt)
{
    const int bid = blockIdx.x;
    const int tid = threadIdx.x;
    if (bid < 192) {
        const int g = bid * 256 + tid;
        *(ush8*)(convwb + (size_t)g * 8) = cvt8(conv_w + (size_t)g * 8);
    } else {
        float4* p = (float4*)pooled;
#pragma unroll
        for (int i = 0; i < 32; ++i)
            p[tid + 256 * i] = make_float4(0.f, 0.f, 0.f, 0.f);
        if (tid < 128) ((int4*)cnt)[tid] = make_int4(0, 0, 0, 0);
    }
}

// ---------------------------------------------------------------------------
// Kernel 2: FUSED recur (blocks 0..7) + pre-GEMM producers (blocks 8..1031)
// + conv_e (blocks 1032..1159).
// pre producers publish per-(dir,sbi) tiles via device-scope release atomics;
// recur consumes with a per-wave contiguous watermark (acquire polls only on
// advance). Ends-first sbi mapping so both chains' early tiles come first.
// LDS padded >81920B to force 1 block/CU (no co-residency on recur CUs).
// ---------------------------------------------------------------------------
#define CSWZ(row, off) ((off) ^ (((row) & 15) << 4))
#define APAD 72

__global__ __launch_bounds__(256, 1) void recur_pre_conve_kernel(
    const float* __restrict__ Wl, const float* __restrict__ Wr,
    const float* __restrict__ cl0, const float* __restrict__ cr0,
    const float* __restrict__ Wsl, const float* __restrict__ Wsr,
    const float* __restrict__ bsl, const float* __restrict__ bl,
    const float* __restrict__ bsr, const float* __restrict__ br,
    const int* __restrict__ x, const float* __restrict__ embed_w,
    float* __restrict__ pre2_l, float* __restrict__ pre2_r,
    unsigned short* __restrict__ outl, unsigned short* __restrict__ outr,
    const unsigned short* __restrict__ convwb,
    unsigned short* __restrict__ hpart,
    int* __restrict__ cnt)
{
    __shared__ alignas(16) unsigned char smem[82048];  // 73728 used; pad->1blk/CU
    __shared__ int xsv[512];

    const int tid  = threadIdx.x;
    const int lane = tid & 63;

    if (blockIdx.x < 8) {
        // ================= recur consumer path =================
        unsigned short* cbf0 = (unsigned short*)smem;
        unsigned short* cbf1 = (unsigned short*)smem + 16 * 256;

        const int dir = blockIdx.x >> 2;
        const int bg  = blockIdx.x & 3;
        const int b0  = bg * 16;
        const int wl  = tid >> 6;
        const int col = lane & 15;
        const int g   = lane >> 4;

        const float* W   = dir ? Wr : Wl;
        const float* c0  = dir ? cr0 : cl0;
        const float* pre = dir ? pre2_r : pre2_l;
        unsigned short* out = dir ? outr : outl;
        int* cbase = cnt + dir * 256;

        // watermark: dir0 -> sbi [0,wm) ready; dir1 -> sbi [256-wm,255] ready
        int wm = 0;
        auto cover = [&](int sNeed) {
            const int sq = sNeed >> 1;
            if (dir == 0) {
                while (wm <= sq) {
                    int c = 0;
                    if (lane == 0)
                        c = __hip_atomic_load(cbase + wm, __ATOMIC_ACQUIRE,
                                              __HIP_MEMORY_SCOPE_AGENT);
                    c = __shfl(c, 0);
                    if (c == 2) ++wm;
                }
            } else {
                while (wm < 256 - sq) {
                    int c = 0;
                    if (lane == 0)
                        c = __hip_atomic_load(cbase + (255 - wm), __ATOMIC_ACQUIRE,
                                              __HIP_MEMORY_SCOPE_AGENT);
                    c = __shfl(c, 0);
                    if (c == 2) ++wm;
                }
            }
        };

        bf16x8 wfrag[4][8];
#pragma unroll
        for (int mt = 0; mt < 4; ++mt)
#pragma unroll
            for (int i = 0; i < 8; ++i) {
                const int kt = (i + 2 * wl) & 7;
                const float* src = W + (size_t)(wl * 64 + mt * 16 + col) * DD
                                     + kt * 32 + g * 8;
                const ush8 p = cvt8(src);
                wfrag[mt][i] = *(bf16x8*)&p;
            }

        int soff[8];
#pragma unroll
        for (int i = 0; i < 8; ++i) {
            const int kt = (i + 2 * wl) & 7;
            soff[i] = CSWZ(col, kt * 64 + g * 16);
        }

        {
            const int blc = tid >> 4;
            const int ch  = tid & 15;
            const float* src = c0 + (size_t)(b0 + blc) * DD + ch * 16;
            const ush8 p0 = cvt8(src);
            const ush8 p1 = cvt8(src + 8);
            char* rowp = (char*)cbf0 + blc * 512;
            *(ush8*)(rowp + CSWZ(blc, ch * 32))      = p0;
            *(ush8*)(rowp + CSWZ(blc, ch * 32 + 16)) = p1;
            const int t0 = dir ? 511 : 0;
            ush8* dst = (ush8*)(out + ((size_t)t0 * BB + b0 + blc) * DD + ch * 16);
            dst[0] = p0; dst[1] = p1;
        }

        const int lpre = (wl * 16 + g) * 64 + col * 4;
        const ptrdiff_t pstep = dir ? -(ptrdiff_t)16384 : (ptrdiff_t)16384;
        const float* p0 = pre + ((size_t)(dir ? 511 : 0) * 4 + bg) * 4096 + lpre;

        cover(dir ? 510 : 1);   // s = {t0, t0 +- 1} published

        float4 pA0 = *(const float4*)(p0);
        float4 pA1 = *(const float4*)(p0 + 256);
        float4 pA2 = *(const float4*)(p0 + 512);
        float4 pA3 = *(const float4*)(p0 + 768);
        const float* p1p = p0 + pstep;
        float4 pB0 = *(const float4*)(p1p);
        float4 pB1 = *(const float4*)(p1p + 256);
        float4 pB2 = *(const float4*)(p1p + 512);
        float4 pB3 = *(const float4*)(p1p + 768);
        const float* pfetch = p0 + 2 * pstep;

        unsigned short* oplane = out + (size_t)(dir ? 510 : 1) * BB * DD
                                     + (b0 + col) * DD + wl * 64 + g * 4;
        const ptrdiff_t ostep = (dir ? -(ptrdiff_t)1 : (ptrdiff_t)1) * (BB * DD);

        __syncthreads();

        int cur = 0;
#pragma unroll 2
        for (int k = 0; k < SS - 1; ++k) {
            bf16x8 sfrag[8];
            {
                const char* rowp = (const char*)(cur ? cbf1 : cbf0) + col * 512;
#pragma unroll
                for (int i = 0; i < 8; ++i)
                    sfrag[i] = *(const bf16x8*)(rowp + soff[i]);
            }

            // pre tile for the pN load must be published
            {
                int sN = dir ? (509 - k) : (k + 2);
                sN = (sN < 1) ? 1 : (sN > 510 ? 510 : sN);
                cover(sN);
            }
            const float4 pN0 = *(const float4*)(pfetch);
            const float4 pN1 = *(const float4*)(pfetch + 256);
            const float4 pN2 = *(const float4*)(pfetch + 512);
            const float4 pN3 = *(const float4*)(pfetch + 768);
            if (k < SS - 4) pfetch += pstep;

            char* nbuf = (char*)(cur ? cbf0 : cbf1) + col * 512;

            auto epi = [&](int mt, const f32x4 a) {
                const float v0 = fmaxf(a[0], 0.f);
                const float v1 = fmaxf(a[1], 0.f);
                const float v2 = fmaxf(a[2], 0.f);
                const float v3 = fmaxf(a[3], 0.f);
                uint2 uu;
                asm("v_cvt_pk_bf16_f32 %0, %1, %2" : "=v"(uu.x) : "v"(v0), "v"(v1));
                asm("v_cvt_pk_bf16_f32 %0, %1, %2" : "=v"(uu.y) : "v"(v2), "v"(v3));
                const int eoff = (wl * 64 + mt * 16 + g * 4) * 2;
                *(uint2*)(nbuf + CSWZ(col, eoff)) = uu;
                *(uint2*)(oplane + mt * 16) = uu;
            };

            f32x4 a0 = *(const f32x4*)&pA0;
            f32x4 a1 = *(const f32x4*)&pA1;
            __builtin_amdgcn_s_setprio(1);
#pragma unroll
            for (int i = 0; i < 8; ++i) {
                a0 = __builtin_amdgcn_mfma_f32_16x16x32_bf16(wfrag[0][i], sfrag[i], a0, 0, 0, 0);
                a1 = __builtin_amdgcn_mfma_f32_16x16x32_bf16(wfrag[1][i], sfrag[i], a1, 0, 0, 0);
            }
            __builtin_amdgcn_s_setprio(0);
            epi(0, a0);
            epi(1, a1);

            f32x4 a2 = *(const f32x4*)&pA2;
            f32x4 a3 = *(const f32x4*)&pA3;
            __builtin_amdgcn_s_setprio(1);
#pragma unroll
            for (int i = 0; i < 8; ++i) {
                a2 = __builtin_amdgcn_mfma_f32_16x16x32_bf16(wfrag[2][i], sfrag[i], a2, 0, 0, 0);
                a3 = __builtin_amdgcn_mfma_f32_16x16x32_bf16(wfrag[3][i], sfrag[i], a3, 0, 0, 0);
            }
            __builtin_amdgcn_s_setprio(0);
            epi(2, a2);
            epi(3, a3);

            pA0 = pB0; pA1 = pB1; pA2 = pB2; pA3 = pB3;
            pB0 = pN0; pB1 = pN1; pB2 = pN2; pB3 = pN3;
            oplane += ostep;

            asm volatile("s_waitcnt lgkmcnt(0)" ::: "memory");
            __builtin_amdgcn_s_barrier();
            asm volatile("" ::: "memory");
            cur ^= 1;
        }
        return;
    }

    if (blockIdx.x < 1032) {
        // ================= pre-GEMM producer path =================
        unsigned short (*Abuf)[128][APAD] = (unsigned short (*)[128][APAD])smem;
        unsigned short (*Bbuf)[128][APAD] =
            (unsigned short (*)[128][APAD])(smem + 2 * 128 * APAD * 2);

        const int j  = blockIdx.x - 8;       // 0..1023
        const int pb = j >> 2;               // 0..255
        const int mi = j & 3;
        const int sbi = (pb & 1) ? 255 - (pb >> 1) : (pb >> 1);  // ends-first

        const int w = tid >> 6;
        const int lr = lane & 15, g = lane >> 4;
        const int lk = g * 8;
        const int strow = tid >> 3;
        const int skc   = (tid & 7) * 8;

        if (tid < 128)
            xsv[tid] = x[(tid & 63) * SS + 2 * sbi + (tid >> 6)];

        f32x4 acc[2][8];
#pragma unroll
        for (int mt = 0; mt < 2; ++mt)
#pragma unroll
            for (int nt = 0; nt < 8; ++nt) acc[mt][nt] = (f32x4)(0.f);

        auto stage = [&](int ks, int buf) {
            const int k0 = ks * 64;
#pragma unroll
            for (int jj = 0; jj < 4; ++jj) {
                const int row = strow + 32 * jj;
                const float* wsrc = (mi < 2 ? Wsl + (size_t)(mi * 128 + row) * DD
                                            : Wsr + (size_t)((mi - 2) * 128 + row) * DD)
                                    + k0 + skc;
                *(ush8*)&Abuf[buf][row][skc] = cvt8(wsrc);
                const float* esrc = embed_w + (size_t)xsv[row] * DD + k0 + skc;
                *(ush8*)&Bbuf[buf][row][skc] = cvt8(esrc);
            }
        };

        __syncthreads();
        stage(0, 0);
        int cur = 0;
        for (int ks = 0; ks < 4; ++ks) {
            __syncthreads();
            if (ks + 1 < 4) stage(ks + 1, cur ^ 1);
#pragma unroll
            for (int k2 = 0; k2 < 2; ++k2) {
                const int kk = k2 * 32 + lk;
                const bf16x8 a0 = *(const bf16x8*)&Abuf[cur][w * 32 + lr][kk];
                const bf16x8 a1 = *(const bf16x8*)&Abuf[cur][w * 32 + 16 + lr][kk];
#pragma unroll
                for (int nt = 0; nt < 8; ++nt) {
                    const bf16x8 bv = *(const bf16x8*)&Bbuf[cur][nt * 16 + lr][kk];
                    acc[0][nt] = __builtin_amdgcn_mfma_f32_16x16x32_bf16(a0, bv, acc[0][nt], 0, 0, 0);
                    acc[1][nt] = __builtin_amdgcn_mfma_f32_16x16x32_bf16(a1, bv, acc[1][nt], 0, 0, 0);
                }
            }
            cur ^= 1;
        }

#pragma unroll
        for (int mt = 0; mt < 2; ++mt) {
            const int eg = mi * 128 + w * 32 + mt * 16 + g * 4;
            const int e  = eg & 255;
            const float* bsx = (eg < 256) ? bsl : bsr;
            const float* bbx = (eg < 256) ? bl  : br;
            const float4 b1 = *(const float4*)(bsx + e);
            const float4 b2 = *(const float4*)(bbx + e);
            float* dstb = (eg >= 256) ? pre2_r : pre2_l;
#pragma unroll
            for (int nt = 0; nt < 8; ++nt) {
                const int sb = sbi * 128 + nt * 16 + lr;
                const int s = sb >> 6, bgq = (sb >> 4) & 3, b_loc = sb & 15;
                float4 v;
                v.x = acc[mt][nt][0] + b1.x + b2.x;
                v.y = acc[mt][nt][1] + b1.y + b2.y;
                v.z = acc[mt][nt][2] + b1.z + b2.z;
                v.w = acc[mt][nt][3] + b1.w + b2.w;
                *(float4*)(dstb + ((size_t)s * 4 + bgq) * 4096 + (e >> 2) * 64 + b_loc * 4) = v;
            }
        }

        // publish: __syncthreads drains all stores to L2; release atomic
        // writes back L2 (cross-XCD visibility) then bumps the flag.
        __syncthreads();
        if (tid == 0)
            __hip_atomic_fetch_add(cnt + (mi >> 1) * 256 + sbi, 1,
                                   __ATOMIC_RELEASE, __HIP_MEMORY_SCOPE_AGENT);
        return;
    }

    // ================= conv_e path (blocks 1032..1159) =================
    unsigned short* Ab = (unsigned short*)smem;
    unsigned short* Bb = (unsigned short*)smem + 2 * 128 * APAD;

    const int wid = tid >> 6;
    const int lr  = lane & 15;
    const int lk  = (lane >> 4) * 8;
    const int strow = tid >> 3;
    const int skc   = (tid & 7) * 8;

    for (int rep = 0; rep < 2; ++rep) {
        const int cid = (blockIdx.x - 1032) + rep * 128;
        const int b   = cid >> 2;
        const int h0  = (cid & 3) * 128;

        for (int i = tid; i < SS; i += 256) xsv[i] = x[b * SS + i];
        __syncthreads();

        f32x4 acc[2][8];
#pragma unroll
        for (int st = 0; st < 2; ++st)
#pragma unroll
            for (int ht = 0; ht < 8; ++ht) acc[st][ht] = (f32x4)(0.f);

        auto stage = [&](int it, int buf) {
            const int stile = it >> 2, kstep = it & 3;
            const int k0 = kstep * 64;
            const int s0 = stile * 128;
#pragma unroll
            for (int jj = 0; jj < 4; ++jj) {
                const int row = strow + 32 * jj;
                const int ss = s0 + row;
                const float* esrc = embed_w + (size_t)xsv[ss] * DD + k0 + skc;
                *(ush8*)&Ab[(buf * 128 + row) * APAD + skc] = cvt8(esrc);
                *(bf16x8*)&Bb[(buf * 128 + row) * APAD + skc] =
                    *(const bf16x8*)(convwb + (size_t)(h0 + row) * K3D + 256 + k0 + skc);
            }
        };

        stage(0, 0);
        int cur = 0;
        for (int it = 0; it < 16; ++it) {
            __syncthreads();
            if (it + 1 < 16) stage(it + 1, cur ^ 1);

            const int wrow0 = wid * 32;
#pragma unroll
            for (int ks = 0; ks < 2; ++ks) {
                const int kk = ks * 32 + lk;
                const bf16x8 a0 = *(const bf16x8*)&Ab[(cur * 128 + wrow0 + lr) * APAD + kk];
                const bf16x8 a1 = *(const bf16x8*)&Ab[(cur * 128 + wrow0 + 16 + lr) * APAD + kk];
#pragma unroll
                for (int ht = 0; ht < 8; ++ht) {
                    const bf16x8 bv = *(const bf16x8*)&Bb[(cur * 128 + ht * 16 + lr) * APAD + kk];
                    acc[0][ht] = __builtin_amdgcn_mfma_f32_16x16x32_bf16(a0, bv, acc[0][ht], 0, 0, 0);
                    acc[1][ht] = __builtin_amdgcn_mfma_f32_16x16x32_bf16(a1, bv, acc[1][ht], 0, 0, 0);
                }
            }
            if ((it & 3) == 3) {
                const int stile = it >> 2;
                unsigned short* hp = hpart + (size_t)(cid * 4 + stile) * 16384;
#pragma unroll
                for (int st = 0; st < 2; ++st)
#pragma unroll
                    for (int ht = 0; ht < 8; ++ht) {
                        uint2 uu;
                        asm("v_cvt_pk_bf16_f32 %0, %1, %2"
                            : "=v"(uu.x) : "v"(acc[st][ht][0]), "v"(acc[st][ht][1]));
                        asm("v_cvt_pk_bf16_f32 %0, %1, %2"
                            : "=v"(uu.y) : "v"(acc[st][ht][2]), "v"(acc[st][ht][3]));
                        const int f = (wid * 2 + st) * 8 + ht;
                        *(uint2*)(hp + f * 256 + lane * 4) = uu;
                        acc[st][ht] = (f32x4)(0.f);
                    }
            }
            cur ^= 1;
        }
        __syncthreads();
    }
}

// ---------------------------------------------------------------------------
// Kernel 3: conv(left|right) + hpart(e) + relu + maxpool (unchanged).
// ---------------------------------------------------------------------------
#define KSTEP 64
#define NKC 8

__global__ __launch_bounds__(256) void conv_pool_kernel(
    const unsigned short* __restrict__ leftb,
    const unsigned short* __restrict__ rightb,
    const unsigned short* __restrict__ convwb,
    const unsigned short* __restrict__ hpart,
    const float* __restrict__ conv_b,
    float* __restrict__ pooled)
{
    __shared__ unsigned short Abuf[2][128][APAD];
    __shared__ unsigned short Bbuf[2][128][APAD];
    __shared__ float red[4][128];

    const int stile = blockIdx.x & 3;
    const int h0i   = (blockIdx.x >> 2) & 3;
    const int b     = blockIdx.x >> 4;
    const int h0    = h0i * 128;
    const int s0    = stile * 128;
    const int tid = threadIdx.x;
    const int wid = tid >> 6;
    const int lane = tid & 63;
    const int lr  = lane & 15;
    const int lk  = (lane >> 4) * 8;
    const int strow = tid >> 3;
    const int skc   = (tid & 7) * 8;

    f32x4 acc[2][8];
    {
        const unsigned short* hp = hpart
            + ((size_t)((b * 4 + h0i) * 4 + stile)) * 16384;
#pragma unroll
        for (int st = 0; st < 2; ++st)
#pragma unroll
            for (int ht = 0; ht < 8; ++ht) {
                const int f = (wid * 2 + st) * 8 + ht;
                const uint2 uu = *(const uint2*)(hp + f * 256 + lane * 4);
                f32x4 v;
                v[0] = __uint_as_float(uu.x << 16);
                v[1] = __uint_as_float(uu.x & 0xffff0000u);
                v[2] = __uint_as_float(uu.y << 16);
                v[3] = __uint_as_float(uu.y & 0xffff0000u);
                acc[st][ht] = v;
            }
    }

    auto stage = [&](int kstep, int buf) {
        const int k0 = kstep * KSTEP;
        const unsigned short* asrc;
        int koff, bcol;
        if (k0 < DD) { asrc = leftb;  koff = k0;      bcol = k0; }
        else         { asrc = rightb; koff = k0 - DD; bcol = k0 + 256; }
#pragma unroll
        for (int j = 0; j < 4; ++j) {
            const int row = strow + 32 * j;
            const int ss = s0 + row;
            *(bf16x8*)&Abuf[buf][row][skc] =
                *(const bf16x8*)(asrc + ((size_t)ss * BB + b) * DD + koff + skc);
            *(bf16x8*)&Bbuf[buf][row][skc] =
                *(const bf16x8*)(convwb + (size_t)(h0 + row) * K3D + bcol + skc);
        }
    };

    stage(0, 0);
    int cur = 0;
    for (int it = 0; it < NKC; ++it) {
        __syncthreads();
        if (it + 1 < NKC) stage(it + 1, cur ^ 1);

        const int wrow0 = wid * 32;
#pragma unroll
        for (int ks = 0; ks < 2; ++ks) {
            const int kk = ks * 32 + lk;
            const bf16x8 a0 = *(const bf16x8*)&Abuf[cur][wrow0 + lr][kk];
            const bf16x8 a1 = *(const bf16x8*)&Abuf[cur][wrow0 + 16 + lr][kk];
#pragma unroll
            for (int ht = 0; ht < 8; ++ht) {
                const bf16x8 bv = *(const bf16x8*)&Bbuf[cur][ht * 16 + lr][kk];
                acc[0][ht] = __builtin_amdgcn_mfma_f32_16x16x32_bf16(a0, bv, acc[0][ht], 0, 0, 0);
                acc[1][ht] = __builtin_amdgcn_mfma_f32_16x16x32_bf16(a1, bv, acc[1][ht], 0, 0, 0);
            }
        }
        cur ^= 1;
    }

    float pmax[8];
#pragma unroll
    for (int ht = 0; ht < 8; ++ht) {
        float m = -INFINITY;
#pragma unroll
        for (int st = 0; st < 2; ++st)
#pragma unroll
            for (int r = 0; r < 4; ++r)
                m = fmaxf(m, acc[st][ht][r]);
        m = fmaxf(m, __shfl_xor(m, 16));
        m = fmaxf(m, __shfl_xor(m, 32));
        if (lane < 16) red[wid][ht * 16 + lane] = m;
    }
    __syncthreads();
    if (tid < 128) {
        const float m = fmaxf(fmaxf(red[0][tid], red[1][tid]),
                              fmaxf(red[2][tid], red[3][tid]));
        const float v = fmaxf(m + conv_b[h0 + tid], 0.f);
        atomicMax((unsigned*)(pooled + (size_t)b * HH + h0 + tid),
                  __float_as_uint(v));
    }
}

// ---------------------------------------------------------------------------
// Kernel 4: final FC.
// ---------------------------------------------------------------------------
__global__ void fc_kernel(const float* __restrict__ pooled,
                          const float* __restrict__ fc_w,
                          const float* __restrict__ fc_b,
                          float* __restrict__ out)
{
    const int t = threadIdx.x;
    if (t >= BB * NCLS) return;
    const int b = t / NCLS, c = t % NCLS;
    float acc = fc_b[c];
    for (int h = 0; h < HH; ++h)
        acc += pooled[(size_t)b * HH + h] * fc_w[(size_t)c * HH + h];
    out[b * NCLS + c] = acc;
}

// ---------------------------------------------------------------------------
extern "C" void kernel_launch(void* const* d_in, const int* in_sizes, int n_in,
                              void* d_out, int out_size, void* d_ws, size_t ws_size,
                              hipStream_t stream)
{
    const int*   x       = (const int*)  d_in[0];
    const float* embed_w = (const float*)d_in[1];
    const float* Wl      = (const float*)d_in[2];
    const float* bl      = (const float*)d_in[3];
    const float* Wsl     = (const float*)d_in[4];
    const float* bsl     = (const float*)d_in[5];
    const float* Wr      = (const float*)d_in[6];
    const float* br      = (const float*)d_in[7];
    const float* Wsr     = (const float*)d_in[8];
    const float* bsr     = (const float*)d_in[9];
    const float* conv_w  = (const float*)d_in[10];
    const float* conv_b  = (const float*)d_in[11];
    const float* fc_w    = (const float*)d_in[12];
    const float* fc_b    = (const float*)d_in[13];
    const float* cl0     = (const float*)d_in[14];
    const float* cr0     = (const float*)d_in[15];
    float* out = (float*)d_out;

    char* ws = (char*)d_ws;
    const size_t SZf = (size_t)SS * BB * DD * sizeof(float);           // 33.55 MB
    const size_t SZh = (size_t)SS * BB * DD * sizeof(unsigned short);  // 16.78 MB
    float*          pre2_l = (float*)(ws);
    float*          pre2_r = (float*)(ws + SZf);
    unsigned short* leftb  = (unsigned short*)(ws + 2 * SZf);
    unsigned short* rightb = (unsigned short*)(ws + 2 * SZf + SZh);
    unsigned short* convwb = (unsigned short*)(ws + 2 * SZf + 2 * SZh);
    float*          pooled = (float*)(ws + 2 * SZf + 2 * SZh + (size_t)HH * K3D * 2);
    unsigned short* hpart  = (unsigned short*)(ws + 2 * SZf + 2 * SZh
                                               + (size_t)HH * K3D * 2
                                               + (size_t)BB * HH * 4);
    int*            cnt    = (int*)(ws + 2 * SZf + 2 * SZh
                                    + (size_t)HH * K3D * 2
                                    + (size_t)BB * HH * 4
                                    + (size_t)1024 * 16384 * 2);

    prep_small_kernel<<<193, 256, 0, stream>>>(conv_w, convwb, pooled, cnt);

    recur_pre_conve_kernel<<<1160, 256, 0, stream>>>(
        Wl, Wr, cl0, cr0, Wsl, Wsr, bsl, bl, bsr, br, x, embed_w,
        pre2_l, pre2_r, leftb, rightb, convwb, hpart, cnt);

    conv_pool_kernel<<<1024, 256, 0, stream>>>(
        leftb, rightb, convwb, hpart, conv_b, pooled);

    fc_kernel<<<1, BB * NCLS, 0, stream>>>(pooled, fc_w, fc_b, out);
}

// Round 16
// 421.600 us; speedup vs baseline: 1.2964x; 1.2964x over previous
//
#include <hip/hip_runtime.h>
#include <hip/hip_bf16.h>

#define VOCAB 50000
#define DD 256
#define NCLS 10
#define BB 64
#define SS 512
#define HH 512
#define K3D 768

typedef __attribute__((ext_vector_type(8))) short bf16x8;
typedef __attribute__((ext_vector_type(8))) unsigned short ush8;
typedef __attribute__((ext_vector_type(4))) float f32x4;

static __device__ __forceinline__ unsigned short f2bf(float f) {
    __hip_bfloat16 h = __float2bfloat16(f);
    return *reinterpret_cast<unsigned short*>(&h);
}

// 8x fp32 -> 8x bf16 via v_cvt_pk_bf16_f32 (RNE, low<-src0).
static __device__ __forceinline__ ush8 cvt8(const float* src) {
    const float4 lo = *(const float4*)(src);
    const float4 hi = *(const float4*)(src + 4);
    uint4 u;
    asm("v_cvt_pk_bf16_f32 %0, %1, %2" : "=v"(u.x) : "v"(lo.x), "v"(lo.y));
    asm("v_cvt_pk_bf16_f32 %0, %1, %2" : "=v"(u.y) : "v"(lo.z), "v"(lo.w));
    asm("v_cvt_pk_bf16_f32 %0, %1, %2" : "=v"(u.z) : "v"(hi.x), "v"(hi.y));
    asm("v_cvt_pk_bf16_f32 %0, %1, %2" : "=v"(u.w) : "v"(hi.z), "v"(hi.w));
    return *reinterpret_cast<ush8*>(&u);
}

// ---------------------------------------------------------------------------
// Kernel 1: prep + pre-GEMM merged.
//   bid < 1024 : pre-GEMM MFMA. XCD-aware mapping: mi = bid>>8, sbi = bid&255
//                so the 4 mi-blocks sharing an sbi (same 128 embed rows) land
//                on the SAME XCD (bids congruent mod 8) -> gather L2-hits.
//   bid < 1216 : conv_w -> bf16 (convwb)
//   bid == 1216: pooled zero-init
// ---------------------------------------------------------------------------
#define PPAD 72

__global__ __launch_bounds__(256) void prep_pre_kernel(
    const float* __restrict__ Wsl, const float* __restrict__ Wsr,
    const float* __restrict__ bsl, const float* __restrict__ bl,
    const float* __restrict__ bsr, const float* __restrict__ br,
    const int* __restrict__ x, const float* __restrict__ embed_w,
    const float* __restrict__ conv_w,
    unsigned short* __restrict__ convwb,
    float* __restrict__ pre2_l, float* __restrict__ pre2_r,
    float* __restrict__ pooled)
{
    __shared__ unsigned short Abuf[2][128][PPAD];
    __shared__ unsigned short Bbuf[2][128][PPAD];
    __shared__ int xs[128];

    const int bid = blockIdx.x;
    const int tid = threadIdx.x;

    if (bid < 1024) {
        // ---------------- pre-GEMM path ----------------
        const int mi  = bid >> 8;      // 0..3  (slow index: same-XCD sbi groups)
        const int sbi = bid & 255;     // 0..255
        const int w = tid >> 6, lane = tid & 63;
        const int lr = lane & 15, g = lane >> 4;
        const int lk = g * 8;
        const int strow = tid >> 3;
        const int skc   = (tid & 7) * 8;

        if (tid < 128)
            xs[tid] = x[(tid & 63) * SS + 2 * sbi + (tid >> 6)];

        f32x4 acc[2][8];
#pragma unroll
        for (int mt = 0; mt < 2; ++mt)
#pragma unroll
            for (int nt = 0; nt < 8; ++nt) acc[mt][nt] = (f32x4)(0.f);

        auto stage = [&](int ks, int buf) {
            const int k0 = ks * 64;
#pragma unroll
            for (int j = 0; j < 4; ++j) {
                const int row = strow + 32 * j;
                const float* wsrc = (mi < 2 ? Wsl + (size_t)(mi * 128 + row) * DD
                                            : Wsr + (size_t)((mi - 2) * 128 + row) * DD)
                                    + k0 + skc;
                *(ush8*)&Abuf[buf][row][skc] = cvt8(wsrc);
                const float* esrc = embed_w + (size_t)xs[row] * DD + k0 + skc;
                *(ush8*)&Bbuf[buf][row][skc] = cvt8(esrc);
            }
        };

        __syncthreads();   // xs visible
        stage(0, 0);
        int cur = 0;
        for (int ks = 0; ks < 4; ++ks) {
            __syncthreads();
            if (ks + 1 < 4) stage(ks + 1, cur ^ 1);
#pragma unroll
            for (int k2 = 0; k2 < 2; ++k2) {
                const int kk = k2 * 32 + lk;
                const bf16x8 a0 = *(const bf16x8*)&Abuf[cur][w * 32 + lr][kk];
                const bf16x8 a1 = *(const bf16x8*)&Abuf[cur][w * 32 + 16 + lr][kk];
#pragma unroll
                for (int nt = 0; nt < 8; ++nt) {
                    const bf16x8 bv = *(const bf16x8*)&Bbuf[cur][nt * 16 + lr][kk];
                    acc[0][nt] = __builtin_amdgcn_mfma_f32_16x16x32_bf16(a0, bv, acc[0][nt], 0, 0, 0);
                    acc[1][nt] = __builtin_amdgcn_mfma_f32_16x16x32_bf16(a1, bv, acc[1][nt], 0, 0, 0);
                }
            }
            cur ^= 1;
        }

#pragma unroll
        for (int mt = 0; mt < 2; ++mt) {
            const int eg = mi * 128 + w * 32 + mt * 16 + g * 4;
            const int e  = eg & 255;
            const float* bsx = (eg < 256) ? bsl : bsr;
            const float* bbx = (eg < 256) ? bl  : br;
            const float4 b1 = *(const float4*)(bsx + e);
            const float4 b2 = *(const float4*)(bbx + e);
            float* dstb = (eg >= 256) ? pre2_r : pre2_l;
#pragma unroll
            for (int nt = 0; nt < 8; ++nt) {
                const int sb = sbi * 128 + nt * 16 + lr;
                const int s = sb >> 6, bgq = (sb >> 4) & 3, b_loc = sb & 15;
                float4 v;
                v.x = acc[mt][nt][0] + b1.x + b2.x;
                v.y = acc[mt][nt][1] + b1.y + b2.y;
                v.z = acc[mt][nt][2] + b1.z + b2.z;
                v.w = acc[mt][nt][3] + b1.w + b2.w;
                *(float4*)(dstb + ((size_t)s * 4 + bgq) * 4096 + (e >> 2) * 64 + b_loc * 4) = v;
            }
        }
    } else if (bid < 1216) {
        // ---------------- conv_w -> bf16 ----------------
        const int g = (bid - 1024) * 256 + tid;
        *(ush8*)(convwb + (size_t)g * 8) = cvt8(conv_w + (size_t)g * 8);
    } else {
        // ---------------- pooled zero-init ----------------
        float4* p = (float4*)pooled;
#pragma unroll
        for (int i = 0; i < 32; ++i)
            p[tid + 256 * i] = make_float4(0.f, 0.f, 0.f, 0.f);
    }
}

// ---------------------------------------------------------------------------
// Kernel 2: FUSED recur (blocks 0..7, frozen R10 structure) + conv_e
// (blocks 8..135): h_e partials = gather(embed) @ conv_w[:,256:512]^T
// -> hpart (bf16), gathered directly from embed_w in recur's shadow.
// ---------------------------------------------------------------------------
#define CSWZ(row, off) ((off) ^ (((row) & 15) << 4))
#define APAD 72

__global__ __launch_bounds__(256, 1) void recur_conve_kernel(
    const float* __restrict__ Wl, const float* __restrict__ Wr,
    const float* __restrict__ cl0, const float* __restrict__ cr0,
    const float* __restrict__ pre2_l, const float* __restrict__ pre2_r,
    unsigned short* __restrict__ outl, unsigned short* __restrict__ outr,
    const int* __restrict__ x, const float* __restrict__ embed_w,
    const unsigned short* __restrict__ convwb,
    unsigned short* __restrict__ hpart)
{
    __shared__ alignas(16) unsigned char smem[2 * 2 * 128 * APAD * 2];  // 73728B
    __shared__ int xsv[512];

    const int tid  = threadIdx.x;
    const int lane = tid & 63;

    if (blockIdx.x < 8) {
        // ================= recur path (frozen) ==========
        unsigned short* cbf0 = (unsigned short*)smem;          // [16*256]
        unsigned short* cbf1 = (unsigned short*)smem + 16 * 256;

        const int dir = blockIdx.x >> 2;
        const int bg  = blockIdx.x & 3;
        const int b0  = bg * 16;
        const int wl  = tid >> 6;
        const int col = lane & 15;
        const int g   = lane >> 4;

        const float* W   = dir ? Wr : Wl;
        const float* c0  = dir ? cr0 : cl0;
        const float* pre = dir ? pre2_r : pre2_l;
        unsigned short* out = dir ? outr : outl;

        bf16x8 wfrag[4][8];
#pragma unroll
        for (int mt = 0; mt < 4; ++mt)
#pragma unroll
            for (int i = 0; i < 8; ++i) {
                const int kt = (i + 2 * wl) & 7;
                const float* src = W + (size_t)(wl * 64 + mt * 16 + col) * DD
                                     + kt * 32 + g * 8;
                const ush8 p = cvt8(src);
                wfrag[mt][i] = *(bf16x8*)&p;
            }

        int soff[8];
#pragma unroll
        for (int i = 0; i < 8; ++i) {
            const int kt = (i + 2 * wl) & 7;
            soff[i] = CSWZ(col, kt * 64 + g * 16);
        }

        {
            const int blc = tid >> 4;
            const int ch  = tid & 15;
            const float* src = c0 + (size_t)(b0 + blc) * DD + ch * 16;
            const ush8 p0 = cvt8(src);
            const ush8 p1 = cvt8(src + 8);
            char* rowp = (char*)cbf0 + blc * 512;
            *(ush8*)(rowp + CSWZ(blc, ch * 32))      = p0;
            *(ush8*)(rowp + CSWZ(blc, ch * 32 + 16)) = p1;
            const int t0 = dir ? 511 : 0;
            ush8* dst = (ush8*)(out + ((size_t)t0 * BB + b0 + blc) * DD + ch * 16);
            dst[0] = p0; dst[1] = p1;
        }

        const int lpre = (wl * 16 + g) * 64 + col * 4;
        const ptrdiff_t pstep = dir ? -(ptrdiff_t)16384 : (ptrdiff_t)16384;
        const float* p0 = pre + ((size_t)(dir ? 511 : 0) * 4 + bg) * 4096 + lpre;

        float4 pA0 = *(const float4*)(p0);
        float4 pA1 = *(const float4*)(p0 + 256);
        float4 pA2 = *(const float4*)(p0 + 512);
        float4 pA3 = *(const float4*)(p0 + 768);
        const float* p1p = p0 + pstep;
        float4 pB0 = *(const float4*)(p1p);
        float4 pB1 = *(const float4*)(p1p + 256);
        float4 pB2 = *(const float4*)(p1p + 512);
        float4 pB3 = *(const float4*)(p1p + 768);
        const float* pfetch = p0 + 2 * pstep;

        unsigned short* oplane = out + (size_t)(dir ? 510 : 1) * BB * DD
                                     + (b0 + col) * DD + wl * 64 + g * 4;
        const ptrdiff_t ostep = (dir ? -(ptrdiff_t)1 : (ptrdiff_t)1) * (BB * DD);

        __syncthreads();

        int cur = 0;
#pragma unroll 2
        for (int k = 0; k < SS - 1; ++k) {
            bf16x8 sfrag[8];
            {
                const char* rowp = (const char*)(cur ? cbf1 : cbf0) + col * 512;
#pragma unroll
                for (int i = 0; i < 8; ++i)
                    sfrag[i] = *(const bf16x8*)(rowp + soff[i]);
            }

            const float4 pN0 = *(const float4*)(pfetch);
            const float4 pN1 = *(const float4*)(pfetch + 256);
            const float4 pN2 = *(const float4*)(pfetch + 512);
            const float4 pN3 = *(const float4*)(pfetch + 768);
            if (k < SS - 4) pfetch += pstep;

            char* nbuf = (char*)(cur ? cbf0 : cbf1) + col * 512;

            auto epi = [&](int mt, const f32x4 a) {
                const float v0 = fmaxf(a[0], 0.f);
                const float v1 = fmaxf(a[1], 0.f);
                const float v2 = fmaxf(a[2], 0.f);
                const float v3 = fmaxf(a[3], 0.f);
                uint2 uu;
                asm("v_cvt_pk_bf16_f32 %0, %1, %2" : "=v"(uu.x) : "v"(v0), "v"(v1));
                asm("v_cvt_pk_bf16_f32 %0, %1, %2" : "=v"(uu.y) : "v"(v2), "v"(v3));
                const int eoff = (wl * 64 + mt * 16 + g * 4) * 2;
                *(uint2*)(nbuf + CSWZ(col, eoff)) = uu;
                *(uint2*)(oplane + mt * 16) = uu;
            };

            f32x4 a0 = *(const f32x4*)&pA0;
            f32x4 a1 = *(const f32x4*)&pA1;
            __builtin_amdgcn_s_setprio(1);
#pragma unroll
            for (int i = 0; i < 8; ++i) {
                a0 = __builtin_amdgcn_mfma_f32_16x16x32_bf16(wfrag[0][i], sfrag[i], a0, 0, 0, 0);
                a1 = __builtin_amdgcn_mfma_f32_16x16x32_bf16(wfrag[1][i], sfrag[i], a1, 0, 0, 0);
            }
            __builtin_amdgcn_s_setprio(0);
            epi(0, a0);
            epi(1, a1);

            f32x4 a2 = *(const f32x4*)&pA2;
            f32x4 a3 = *(const f32x4*)&pA3;
            __builtin_amdgcn_s_setprio(1);
#pragma unroll
            for (int i = 0; i < 8; ++i) {
                a2 = __builtin_amdgcn_mfma_f32_16x16x32_bf16(wfrag[2][i], sfrag[i], a2, 0, 0, 0);
                a3 = __builtin_amdgcn_mfma_f32_16x16x32_bf16(wfrag[3][i], sfrag[i], a3, 0, 0, 0);
            }
            __builtin_amdgcn_s_setprio(0);
            epi(2, a2);
            epi(3, a3);

            pA0 = pB0; pA1 = pB1; pA2 = pB2; pA3 = pB3;
            pB0 = pN0; pB1 = pN1; pB2 = pN2; pB3 = pN3;
            oplane += ostep;

            asm volatile("s_waitcnt lgkmcnt(0)" ::: "memory");
            __builtin_amdgcn_s_barrier();
            asm volatile("" ::: "memory");
            cur ^= 1;
        }
        return;
    }

    // ===================== conv_e path (blocks 8..135) =====================
    unsigned short* Ab = (unsigned short*)smem;                    // [2][128][APAD]
    unsigned short* Bb = (unsigned short*)smem + 2 * 128 * APAD;

    const int wid = tid >> 6;
    const int lr  = lane & 15;
    const int lk  = (lane >> 4) * 8;
    const int strow = tid >> 3;
    const int skc   = (tid & 7) * 8;

    for (int rep = 0; rep < 2; ++rep) {
        const int cid = (blockIdx.x - 8) + rep * 128;
        const int b   = cid >> 2;
        const int h0  = (cid & 3) * 128;

        // per-batch gather table
        for (int i = tid; i < SS; i += 256) xsv[i] = x[b * SS + i];
        __syncthreads();

        f32x4 acc[2][8];
#pragma unroll
        for (int st = 0; st < 2; ++st)
#pragma unroll
            for (int ht = 0; ht < 8; ++ht) acc[st][ht] = (f32x4)(0.f);

        auto stage = [&](int it, int buf) {
            const int stile = it >> 2, kstep = it & 3;
            const int k0 = kstep * 64;
            const int s0 = stile * 128;
#pragma unroll
            for (int j = 0; j < 4; ++j) {
                const int row = strow + 32 * j;
                const int ss = s0 + row;
                const float* esrc = embed_w + (size_t)xsv[ss] * DD + k0 + skc;
                *(ush8*)&Ab[(buf * 128 + row) * APAD + skc] = cvt8(esrc);
                *(bf16x8*)&Bb[(buf * 128 + row) * APAD + skc] =
                    *(const bf16x8*)(convwb + (size_t)(h0 + row) * K3D + 256 + k0 + skc);
            }
        };

        stage(0, 0);
        int cur = 0;
        for (int it = 0; it < 16; ++it) {
            __syncthreads();
            if (it + 1 < 16) stage(it + 1, cur ^ 1);

            const int wrow0 = wid * 32;
#pragma unroll
            for (int ks = 0; ks < 2; ++ks) {
                const int kk = ks * 32 + lk;
                const bf16x8 a0 = *(const bf16x8*)&Ab[(cur * 128 + wrow0 + lr) * APAD + kk];
                const bf16x8 a1 = *(const bf16x8*)&Ab[(cur * 128 + wrow0 + 16 + lr) * APAD + kk];
#pragma unroll
                for (int ht = 0; ht < 8; ++ht) {
                    const bf16x8 bv = *(const bf16x8*)&Bb[(cur * 128 + ht * 16 + lr) * APAD + kk];
                    acc[0][ht] = __builtin_amdgcn_mfma_f32_16x16x32_bf16(a0, bv, acc[0][ht], 0, 0, 0);
                    acc[1][ht] = __builtin_amdgcn_mfma_f32_16x16x32_bf16(a1, bv, acc[1][ht], 0, 0, 0);
                }
            }
            if ((it & 3) == 3) {
                const int stile = it >> 2;
                unsigned short* hp = hpart + (size_t)(cid * 4 + stile) * 16384;
#pragma unroll
                for (int st = 0; st < 2; ++st)
#pragma unroll
                    for (int ht = 0; ht < 8; ++ht) {
                        uint2 uu;
                        asm("v_cvt_pk_bf16_f32 %0, %1, %2"
                            : "=v"(uu.x) : "v"(acc[st][ht][0]), "v"(acc[st][ht][1]));
                        asm("v_cvt_pk_bf16_f32 %0, %1, %2"
                            : "=v"(uu.y) : "v"(acc[st][ht][2]), "v"(acc[st][ht][3]));
                        const int f = (wid * 2 + st) * 8 + ht;
                        *(uint2*)(hp + f * 256 + lane * 4) = uu;
                        acc[st][ht] = (f32x4)(0.f);
                    }
            }
            cur ^= 1;
        }
        __syncthreads();
    }
}

// ---------------------------------------------------------------------------
// Kernel 3: conv(left|right) + hpart(e) + relu + maxpool.
// grid = 1024 (b, h0, stile); per-block partial max -> pooled via atomicMax
// on the fp32 bit-pattern (all values >= 0 post-relu => valid).
// ---------------------------------------------------------------------------
#define KSTEP 64
#define NKC 8

__global__ __launch_bounds__(256) void conv_pool_kernel(
    const unsigned short* __restrict__ leftb,
    const unsigned short* __restrict__ rightb,
    const unsigned short* __restrict__ convwb,
    const unsigned short* __restrict__ hpart,
    const float* __restrict__ conv_b,
    float* __restrict__ pooled)
{
    __shared__ unsigned short Abuf[2][128][APAD];
    __shared__ unsigned short Bbuf[2][128][APAD];
    __shared__ float red[4][128];

    const int stile = blockIdx.x & 3;
    const int h0i   = (blockIdx.x >> 2) & 3;
    const int b     = blockIdx.x >> 4;
    const int h0    = h0i * 128;
    const int s0    = stile * 128;
    const int tid = threadIdx.x;
    const int wid = tid >> 6;
    const int lane = tid & 63;
    const int lr  = lane & 15;
    const int lk  = (lane >> 4) * 8;
    const int strow = tid >> 3;
    const int skc   = (tid & 7) * 8;

    f32x4 acc[2][8];
    {
        const unsigned short* hp = hpart
            + ((size_t)((b * 4 + h0i) * 4 + stile)) * 16384;
#pragma unroll
        for (int st = 0; st < 2; ++st)
#pragma unroll
            for (int ht = 0; ht < 8; ++ht) {
                const int f = (wid * 2 + st) * 8 + ht;
                const uint2 uu = *(const uint2*)(hp + f * 256 + lane * 4);
                f32x4 v;
                v[0] = __uint_as_float(uu.x << 16);
                v[1] = __uint_as_float(uu.x & 0xffff0000u);
                v[2] = __uint_as_float(uu.y << 16);
                v[3] = __uint_as_float(uu.y & 0xffff0000u);
                acc[st][ht] = v;
            }
    }

    auto stage = [&](int kstep, int buf) {
        const int k0 = kstep * KSTEP;
        const unsigned short* asrc;
        int koff, bcol;
        if (k0 < DD) { asrc = leftb;  koff = k0;      bcol = k0; }
        else         { asrc = rightb; koff = k0 - DD; bcol = k0 + 256; }
#pragma unroll
        for (int j = 0; j < 4; ++j) {
            const int row = strow + 32 * j;
            const int ss = s0 + row;
            *(bf16x8*)&Abuf[buf][row][skc] =
                *(const bf16x8*)(asrc + ((size_t)ss * BB + b) * DD + koff + skc);
            *(bf16x8*)&Bbuf[buf][row][skc] =
                *(const bf16x8*)(convwb + (size_t)(h0 + row) * K3D + bcol + skc);
        }
    };

    stage(0, 0);
    int cur = 0;
    for (int it = 0; it < NKC; ++it) {
        __syncthreads();
        if (it + 1 < NKC) stage(it + 1, cur ^ 1);

        const int wrow0 = wid * 32;
#pragma unroll
        for (int ks = 0; ks < 2; ++ks) {
            const int kk = ks * 32 + lk;
            const bf16x8 a0 = *(const bf16x8*)&Abuf[cur][wrow0 + lr][kk];
            const bf16x8 a1 = *(const bf16x8*)&Abuf[cur][wrow0 + 16 + lr][kk];
#pragma unroll
            for (int ht = 0; ht < 8; ++ht) {
                const bf16x8 bv = *(const bf16x8*)&Bbuf[cur][ht * 16 + lr][kk];
                acc[0][ht] = __builtin_amdgcn_mfma_f32_16x16x32_bf16(a0, bv, acc[0][ht], 0, 0, 0);
                acc[1][ht] = __builtin_amdgcn_mfma_f32_16x16x32_bf16(a1, bv, acc[1][ht], 0, 0, 0);
            }
        }
        cur ^= 1;
    }

    float pmax[8];
#pragma unroll
    for (int ht = 0; ht < 8; ++ht) {
        float m = -INFINITY;
#pragma unroll
        for (int st = 0; st < 2; ++st)
#pragma unroll
            for (int r = 0; r < 4; ++r)
                m = fmaxf(m, acc[st][ht][r]);
        m = fmaxf(m, __shfl_xor(m, 16));
        m = fmaxf(m, __shfl_xor(m, 32));
        if (lane < 16) red[wid][ht * 16 + lane] = m;
    }
    __syncthreads();
    if (tid < 128) {
        const float m = fmaxf(fmaxf(red[0][tid], red[1][tid]),
                              fmaxf(red[2][tid], red[3][tid]));
        const float v = fmaxf(m + conv_b[h0 + tid], 0.f);
        atomicMax((unsigned*)(pooled + (size_t)b * HH + h0 + tid),
                  __float_as_uint(v));
    }
}

// ---------------------------------------------------------------------------
// Kernel 4: final FC.
// ---------------------------------------------------------------------------
__global__ void fc_kernel(const float* __restrict__ pooled,
                          const float* __restrict__ fc_w,
                          const float* __restrict__ fc_b,
                          float* __restrict__ out)
{
    const int t = threadIdx.x;
    if (t >= BB * NCLS) return;
    const int b = t / NCLS, c = t % NCLS;
    float acc = fc_b[c];
    for (int h = 0; h < HH; ++h)
        acc += pooled[(size_t)b * HH + h] * fc_w[(size_t)c * HH + h];
    out[b * NCLS + c] = acc;
}

// ---------------------------------------------------------------------------
extern "C" void kernel_launch(void* const* d_in, const int* in_sizes, int n_in,
                              void* d_out, int out_size, void* d_ws, size_t ws_size,
                              hipStream_t stream)
{
    const int*   x       = (const int*)  d_in[0];
    const float* embed_w = (const float*)d_in[1];
    const float* Wl      = (const float*)d_in[2];
    const float* bl      = (const float*)d_in[3];
    const float* Wsl     = (const float*)d_in[4];
    const float* bsl     = (const float*)d_in[5];
    const float* Wr      = (const float*)d_in[6];
    const float* br      = (const float*)d_in[7];
    const float* Wsr     = (const float*)d_in[8];
    const float* bsr     = (const float*)d_in[9];
    const float* conv_w  = (const float*)d_in[10];
    const float* conv_b  = (const float*)d_in[11];
    const float* fc_w    = (const float*)d_in[12];
    const float* fc_b    = (const float*)d_in[13];
    const float* cl0     = (const float*)d_in[14];
    const float* cr0     = (const float*)d_in[15];
    float* out = (float*)d_out;

    char* ws = (char*)d_ws;
    const size_t SZf = (size_t)SS * BB * DD * sizeof(float);           // 33.55 MB
    const size_t SZh = (size_t)SS * BB * DD * sizeof(unsigned short);  // 16.78 MB
    float*          pre2_l = (float*)(ws);
    float*          pre2_r = (float*)(ws + SZf);
    unsigned short* leftb  = (unsigned short*)(ws + 2 * SZf);
    unsigned short* rightb = (unsigned short*)(ws + 2 * SZf + SZh);
    unsigned short* convwb = (unsigned short*)(ws + 2 * SZf + 2 * SZh);
    float*          pooled = (float*)(ws + 2 * SZf + 2 * SZh + (size_t)HH * K3D * 2);
    unsigned short* hpart  = (unsigned short*)(ws + 2 * SZf + 2 * SZh
                                               + (size_t)HH * K3D * 2
                                               + (size_t)BB * HH * 4);

    prep_pre_kernel<<<1217, 256, 0, stream>>>(
        Wsl, Wsr, bsl, bl, bsr, br, x, embed_w, conv_w,
        convwb, pre2_l, pre2_r, pooled);

    recur_conve_kernel<<<136, 256, 0, stream>>>(
        Wl, Wr, cl0, cr0, pre2_l, pre2_r, leftb, rightb,
        x, embed_w, convwb, hpart);

    conv_pool_kernel<<<1024, 256, 0, stream>>>(
        leftb, rightb, convwb, hpart, conv_b, pooled);

    fc_kernel<<<1, BB * NCLS, 0, stream>>>(pooled, fc_w, fc_b, out);
}

// Round 17
// 369.534 us; speedup vs baseline: 1.4790x; 1.1409x over previous
//
#include <hip/hip_runtime.h>
#include <hip/hip_bf16.h>

#define VOCAB 50000
#define DD 256
#define NCLS 10
#define BB 64
#define SS 512
#define HH 512
#define K3D 768

typedef __attribute__((ext_vector_type(8))) short bf16x8;
typedef __attribute__((ext_vector_type(8))) unsigned short ush8;
typedef __attribute__((ext_vector_type(4))) float f32x4;

static __device__ __forceinline__ unsigned short f2bf(float f) {
    __hip_bfloat16 h = __float2bfloat16(f);
    return *reinterpret_cast<unsigned short*>(&h);
}

// 8x fp32 -> 8x bf16 via v_cvt_pk_bf16_f32 (RNE, low<-src0).
static __device__ __forceinline__ ush8 cvt8(const float* src) {
    const float4 lo = *(const float4*)(src);
    const float4 hi = *(const float4*)(src + 4);
    uint4 u;
    asm("v_cvt_pk_bf16_f32 %0, %1, %2" : "=v"(u.x) : "v"(lo.x), "v"(lo.y));
    asm("v_cvt_pk_bf16_f32 %0, %1, %2" : "=v"(u.y) : "v"(lo.z), "v"(lo.w));
    asm("v_cvt_pk_bf16_f32 %0, %1, %2" : "=v"(u.z) : "v"(hi.x), "v"(hi.y));
    asm("v_cvt_pk_bf16_f32 %0, %1, %2" : "=v"(u.w) : "v"(hi.z), "v"(hi.w));
    return *reinterpret_cast<ush8*>(&u);
}

// 4x bf16 (uint2) -> f32x4 (bit-shift unpack; exact)
static __device__ __forceinline__ f32x4 unpk(uint2 u) {
    f32x4 v;
    v[0] = __uint_as_float(u.x << 16);
    v[1] = __uint_as_float(u.x & 0xffff0000u);
    v[2] = __uint_as_float(u.y << 16);
    v[3] = __uint_as_float(u.y & 0xffff0000u);
    return v;
}

// ---------------------------------------------------------------------------
// Kernel 1: prep + pre-GEMM merged. pre2 now stored BF16 (halved traffic).
//   bid < 1024 : pre-GEMM MFMA; XCD-aware: mi = bid>>8, sbi = bid&255.
//   bid < 1216 : conv_w -> bf16 (convwb)
//   bid == 1216: pooled zero-init
// ---------------------------------------------------------------------------
#define PPAD 72

__global__ __launch_bounds__(256) void prep_pre_kernel(
    const float* __restrict__ Wsl, const float* __restrict__ Wsr,
    const float* __restrict__ bsl, const float* __restrict__ bl,
    const float* __restrict__ bsr, const float* __restrict__ br,
    const int* __restrict__ x, const float* __restrict__ embed_w,
    const float* __restrict__ conv_w,
    unsigned short* __restrict__ convwb,
    unsigned short* __restrict__ pre2_l, unsigned short* __restrict__ pre2_r,
    float* __restrict__ pooled)
{
    __shared__ unsigned short Abuf[2][128][PPAD];
    __shared__ unsigned short Bbuf[2][128][PPAD];
    __shared__ int xs[128];

    const int bid = blockIdx.x;
    const int tid = threadIdx.x;

    if (bid < 1024) {
        // ---------------- pre-GEMM path ----------------
        const int mi  = bid >> 8;      // 0..3 (same-XCD sbi groups)
        const int sbi = bid & 255;     // 0..255
        const int w = tid >> 6, lane = tid & 63;
        const int lr = lane & 15, g = lane >> 4;
        const int lk = g * 8;
        const int strow = tid >> 3;
        const int skc   = (tid & 7) * 8;

        if (tid < 128)
            xs[tid] = x[(tid & 63) * SS + 2 * sbi + (tid >> 6)];

        f32x4 acc[2][8];
#pragma unroll
        for (int mt = 0; mt < 2; ++mt)
#pragma unroll
            for (int nt = 0; nt < 8; ++nt) acc[mt][nt] = (f32x4)(0.f);

        auto stage = [&](int ks, int buf) {
            const int k0 = ks * 64;
#pragma unroll
            for (int j = 0; j < 4; ++j) {
                const int row = strow + 32 * j;
                const float* wsrc = (mi < 2 ? Wsl + (size_t)(mi * 128 + row) * DD
                                            : Wsr + (size_t)((mi - 2) * 128 + row) * DD)
                                    + k0 + skc;
                *(ush8*)&Abuf[buf][row][skc] = cvt8(wsrc);
                const float* esrc = embed_w + (size_t)xs[row] * DD + k0 + skc;
                *(ush8*)&Bbuf[buf][row][skc] = cvt8(esrc);
            }
        };

        __syncthreads();   // xs visible
        stage(0, 0);
        int cur = 0;
        for (int ks = 0; ks < 4; ++ks) {
            __syncthreads();
            if (ks + 1 < 4) stage(ks + 1, cur ^ 1);
#pragma unroll
            for (int k2 = 0; k2 < 2; ++k2) {
                const int kk = k2 * 32 + lk;
                const bf16x8 a0 = *(const bf16x8*)&Abuf[cur][w * 32 + lr][kk];
                const bf16x8 a1 = *(const bf16x8*)&Abuf[cur][w * 32 + 16 + lr][kk];
#pragma unroll
                for (int nt = 0; nt < 8; ++nt) {
                    const bf16x8 bv = *(const bf16x8*)&Bbuf[cur][nt * 16 + lr][kk];
                    acc[0][nt] = __builtin_amdgcn_mfma_f32_16x16x32_bf16(a0, bv, acc[0][nt], 0, 0, 0);
                    acc[1][nt] = __builtin_amdgcn_mfma_f32_16x16x32_bf16(a1, bv, acc[1][nt], 0, 0, 0);
                }
            }
            cur ^= 1;
        }

#pragma unroll
        for (int mt = 0; mt < 2; ++mt) {
            const int eg = mi * 128 + w * 32 + mt * 16 + g * 4;
            const int e  = eg & 255;
            const float* bsx = (eg < 256) ? bsl : bsr;
            const float* bbx = (eg < 256) ? bl  : br;
            const float4 b1 = *(const float4*)(bsx + e);
            const float4 b2 = *(const float4*)(bbx + e);
            unsigned short* dstb = (eg >= 256) ? pre2_r : pre2_l;
#pragma unroll
            for (int nt = 0; nt < 8; ++nt) {
                const int sb = sbi * 128 + nt * 16 + lr;
                const int s = sb >> 6, bgq = (sb >> 4) & 3, b_loc = sb & 15;
                const float vx = acc[mt][nt][0] + b1.x + b2.x;
                const float vy = acc[mt][nt][1] + b1.y + b2.y;
                const float vz = acc[mt][nt][2] + b1.z + b2.z;
                const float vw = acc[mt][nt][3] + b1.w + b2.w;
                uint2 uu;
                asm("v_cvt_pk_bf16_f32 %0, %1, %2" : "=v"(uu.x) : "v"(vx), "v"(vy));
                asm("v_cvt_pk_bf16_f32 %0, %1, %2" : "=v"(uu.y) : "v"(vz), "v"(vw));
                *(uint2*)(dstb + ((size_t)s * 4 + bgq) * 4096 + (e >> 2) * 64 + b_loc * 4) = uu;
            }
        }
    } else if (bid < 1216) {
        // ---------------- conv_w -> bf16 ----------------
        const int g = (bid - 1024) * 256 + tid;
        *(ush8*)(convwb + (size_t)g * 8) = cvt8(conv_w + (size_t)g * 8);
    } else {
        // ---------------- pooled zero-init ----------------
        float4* p = (float4*)pooled;
#pragma unroll
        for (int i = 0; i < 32; ++i)
            p[tid + 256 * i] = make_float4(0.f, 0.f, 0.f, 0.f);
    }
}

// ---------------------------------------------------------------------------
// Kernel 2: FUSED recur (blocks 0..7, frozen R10 structure; pre2 now bf16,
// unpacked at acc-init — off critical path) + conv_e (blocks 8..135).
// ---------------------------------------------------------------------------
#define CSWZ(row, off) ((off) ^ (((row) & 15) << 4))
#define APAD 72

__global__ __launch_bounds__(256, 1) void recur_conve_kernel(
    const float* __restrict__ Wl, const float* __restrict__ Wr,
    const float* __restrict__ cl0, const float* __restrict__ cr0,
    const unsigned short* __restrict__ pre2_l,
    const unsigned short* __restrict__ pre2_r,
    unsigned short* __restrict__ outl, unsigned short* __restrict__ outr,
    const int* __restrict__ x, const float* __restrict__ embed_w,
    const unsigned short* __restrict__ convwb,
    unsigned short* __restrict__ hpart)
{
    __shared__ alignas(16) unsigned char smem[2 * 2 * 128 * APAD * 2];  // 73728B
    __shared__ int xsv[512];

    const int tid  = threadIdx.x;
    const int lane = tid & 63;

    if (blockIdx.x < 8) {
        // ================= recur path (frozen) ==========
        unsigned short* cbf0 = (unsigned short*)smem;          // [16*256]
        unsigned short* cbf1 = (unsigned short*)smem + 16 * 256;

        const int dir = blockIdx.x >> 2;
        const int bg  = blockIdx.x & 3;
        const int b0  = bg * 16;
        const int wl  = tid >> 6;
        const int col = lane & 15;
        const int g   = lane >> 4;

        const float* W   = dir ? Wr : Wl;
        const float* c0  = dir ? cr0 : cl0;
        const unsigned short* pre = dir ? pre2_r : pre2_l;
        unsigned short* out = dir ? outr : outl;

        bf16x8 wfrag[4][8];
#pragma unroll
        for (int mt = 0; mt < 4; ++mt)
#pragma unroll
            for (int i = 0; i < 8; ++i) {
                const int kt = (i + 2 * wl) & 7;
                const float* src = W + (size_t)(wl * 64 + mt * 16 + col) * DD
                                     + kt * 32 + g * 8;
                const ush8 p = cvt8(src);
                wfrag[mt][i] = *(bf16x8*)&p;
            }

        int soff[8];
#pragma unroll
        for (int i = 0; i < 8; ++i) {
            const int kt = (i + 2 * wl) & 7;
            soff[i] = CSWZ(col, kt * 64 + g * 16);
        }

        {
            const int blc = tid >> 4;
            const int ch  = tid & 15;
            const float* src = c0 + (size_t)(b0 + blc) * DD + ch * 16;
            const ush8 p0 = cvt8(src);
            const ush8 p1 = cvt8(src + 8);
            char* rowp = (char*)cbf0 + blc * 512;
            *(ush8*)(rowp + CSWZ(blc, ch * 32))      = p0;
            *(ush8*)(rowp + CSWZ(blc, ch * 32 + 16)) = p1;
            const int t0 = dir ? 511 : 0;
            ush8* dst = (ush8*)(out + ((size_t)t0 * BB + b0 + blc) * DD + ch * 16);
            dst[0] = p0; dst[1] = p1;
        }

        const int lpre = (wl * 16 + g) * 64 + col * 4;
        const ptrdiff_t pstep = dir ? -(ptrdiff_t)16384 : (ptrdiff_t)16384;
        const unsigned short* p0 = pre
            + ((size_t)(dir ? 511 : 0) * 4 + bg) * 4096 + lpre;

        uint2 pA0 = *(const uint2*)(p0);
        uint2 pA1 = *(const uint2*)(p0 + 256);
        uint2 pA2 = *(const uint2*)(p0 + 512);
        uint2 pA3 = *(const uint2*)(p0 + 768);
        const unsigned short* p1p = p0 + pstep;
        uint2 pB0 = *(const uint2*)(p1p);
        uint2 pB1 = *(const uint2*)(p1p + 256);
        uint2 pB2 = *(const uint2*)(p1p + 512);
        uint2 pB3 = *(const uint2*)(p1p + 768);
        const unsigned short* pfetch = p0 + 2 * pstep;

        unsigned short* oplane = out + (size_t)(dir ? 510 : 1) * BB * DD
                                     + (b0 + col) * DD + wl * 64 + g * 4;
        const ptrdiff_t ostep = (dir ? -(ptrdiff_t)1 : (ptrdiff_t)1) * (BB * DD);

        __syncthreads();

        int cur = 0;
#pragma unroll 2
        for (int k = 0; k < SS - 1; ++k) {
            bf16x8 sfrag[8];
            {
                const char* rowp = (const char*)(cur ? cbf1 : cbf0) + col * 512;
#pragma unroll
                for (int i = 0; i < 8; ++i)
                    sfrag[i] = *(const bf16x8*)(rowp + soff[i]);
            }

            const uint2 pN0 = *(const uint2*)(pfetch);
            const uint2 pN1 = *(const uint2*)(pfetch + 256);
            const uint2 pN2 = *(const uint2*)(pfetch + 512);
            const uint2 pN3 = *(const uint2*)(pfetch + 768);
            if (k < SS - 4) pfetch += pstep;

            char* nbuf = (char*)(cur ? cbf0 : cbf1) + col * 512;

            auto epi = [&](int mt, const f32x4 a) {
                const float v0 = fmaxf(a[0], 0.f);
                const float v1 = fmaxf(a[1], 0.f);
                const float v2 = fmaxf(a[2], 0.f);
                const float v3 = fmaxf(a[3], 0.f);
                uint2 uu;
                asm("v_cvt_pk_bf16_f32 %0, %1, %2" : "=v"(uu.x) : "v"(v0), "v"(v1));
                asm("v_cvt_pk_bf16_f32 %0, %1, %2" : "=v"(uu.y) : "v"(v2), "v"(v3));
                const int eoff = (wl * 64 + mt * 16 + g * 4) * 2;
                *(uint2*)(nbuf + CSWZ(col, eoff)) = uu;
                *(uint2*)(oplane + mt * 16) = uu;
            };

            f32x4 a0 = unpk(pA0);
            f32x4 a1 = unpk(pA1);
            __builtin_amdgcn_s_setprio(1);
#pragma unroll
            for (int i = 0; i < 8; ++i) {
                a0 = __builtin_amdgcn_mfma_f32_16x16x32_bf16(wfrag[0][i], sfrag[i], a0, 0, 0, 0);
                a1 = __builtin_amdgcn_mfma_f32_16x16x32_bf16(wfrag[1][i], sfrag[i], a1, 0, 0, 0);
            }
            __builtin_amdgcn_s_setprio(0);
            epi(0, a0);
            epi(1, a1);

            f32x4 a2 = unpk(pA2);
            f32x4 a3 = unpk(pA3);
            __builtin_amdgcn_s_setprio(1);
#pragma unroll
            for (int i = 0; i < 8; ++i) {
                a2 = __builtin_amdgcn_mfma_f32_16x16x32_bf16(wfrag[2][i], sfrag[i], a2, 0, 0, 0);
                a3 = __builtin_amdgcn_mfma_f32_16x16x32_bf16(wfrag[3][i], sfrag[i], a3, 0, 0, 0);
            }
            __builtin_amdgcn_s_setprio(0);
            epi(2, a2);
            epi(3, a3);

            pA0 = pB0; pA1 = pB1; pA2 = pB2; pA3 = pB3;
            pB0 = pN0; pB1 = pN1; pB2 = pN2; pB3 = pN3;
            oplane += ostep;

            asm volatile("s_waitcnt lgkmcnt(0)" ::: "memory");
            __builtin_amdgcn_s_barrier();
            asm volatile("" ::: "memory");
            cur ^= 1;
        }
        return;
    }

    // ===================== conv_e path (blocks 8..135) =====================
    unsigned short* Ab = (unsigned short*)smem;                    // [2][128][APAD]
    unsigned short* Bb = (unsigned short*)smem + 2 * 128 * APAD;

    const int wid = tid >> 6;
    const int lr  = lane & 15;
    const int lk  = (lane >> 4) * 8;
    const int strow = tid >> 3;
    const int skc   = (tid & 7) * 8;

    for (int rep = 0; rep < 2; ++rep) {
        const int cid = (blockIdx.x - 8) + rep * 128;
        const int b   = cid >> 2;
        const int h0  = (cid & 3) * 128;

        // per-batch gather table
        for (int i = tid; i < SS; i += 256) xsv[i] = x[b * SS + i];
        __syncthreads();

        f32x4 acc[2][8];
#pragma unroll
        for (int st = 0; st < 2; ++st)
#pragma unroll
            for (int ht = 0; ht < 8; ++ht) acc[st][ht] = (f32x4)(0.f);

        auto stage = [&](int it, int buf) {
            const int stile = it >> 2, kstep = it & 3;
            const int k0 = kstep * 64;
            const int s0 = stile * 128;
#pragma unroll
            for (int j = 0; j < 4; ++j) {
                const int row = strow + 32 * j;
                const int ss = s0 + row;
                const float* esrc = embed_w + (size_t)xsv[ss] * DD + k0 + skc;
                *(ush8*)&Ab[(buf * 128 + row) * APAD + skc] = cvt8(esrc);
                *(bf16x8*)&Bb[(buf * 128 + row) * APAD + skc] =
                    *(const bf16x8*)(convwb + (size_t)(h0 + row) * K3D + 256 + k0 + skc);
            }
        };

        stage(0, 0);
        int cur = 0;
        for (int it = 0; it < 16; ++it) {
            __syncthreads();
            if (it + 1 < 16) stage(it + 1, cur ^ 1);

            const int wrow0 = wid * 32;
#pragma unroll
            for (int ks = 0; ks < 2; ++ks) {
                const int kk = ks * 32 + lk;
                const bf16x8 a0 = *(const bf16x8*)&Ab[(cur * 128 + wrow0 + lr) * APAD + kk];
                const bf16x8 a1 = *(const bf16x8*)&Ab[(cur * 128 + wrow0 + 16 + lr) * APAD + kk];
#pragma unroll
                for (int ht = 0; ht < 8; ++ht) {
                    const bf16x8 bv = *(const bf16x8*)&Bb[(cur * 128 + ht * 16 + lr) * APAD + kk];
                    acc[0][ht] = __builtin_amdgcn_mfma_f32_16x16x32_bf16(a0, bv, acc[0][ht], 0, 0, 0);
                    acc[1][ht] = __builtin_amdgcn_mfma_f32_16x16x32_bf16(a1, bv, acc[1][ht], 0, 0, 0);
                }
            }
            if ((it & 3) == 3) {
                const int stile = it >> 2;
                unsigned short* hp = hpart + (size_t)(cid * 4 + stile) * 16384;
#pragma unroll
                for (int st = 0; st < 2; ++st)
#pragma unroll
                    for (int ht = 0; ht < 8; ++ht) {
                        uint2 uu;
                        asm("v_cvt_pk_bf16_f32 %0, %1, %2"
                            : "=v"(uu.x) : "v"(acc[st][ht][0]), "v"(acc[st][ht][1]));
                        asm("v_cvt_pk_bf16_f32 %0, %1, %2"
                            : "=v"(uu.y) : "v"(acc[st][ht][2]), "v"(acc[st][ht][3]));
                        const int f = (wid * 2 + st) * 8 + ht;
                        *(uint2*)(hp + f * 256 + lane * 4) = uu;
                        acc[st][ht] = (f32x4)(0.f);
                    }
            }
            cur ^= 1;
        }
        __syncthreads();
    }
}

// ---------------------------------------------------------------------------
// Kernel 3: conv(left|right) + hpart(e) + relu + maxpool (unchanged).
// ---------------------------------------------------------------------------
#define KSTEP 64
#define NKC 8

__global__ __launch_bounds__(256) void conv_pool_kernel(
    const unsigned short* __restrict__ leftb,
    const unsigned short* __restrict__ rightb,
    const unsigned short* __restrict__ convwb,
    const unsigned short* __restrict__ hpart,
    const float* __restrict__ conv_b,
    float* __restrict__ pooled)
{
    __shared__ unsigned short Abuf[2][128][APAD];
    __shared__ unsigned short Bbuf[2][128][APAD];
    __shared__ float red[4][128];

    const int stile = blockIdx.x & 3;
    const int h0i   = (blockIdx.x >> 2) & 3;
    const int b     = blockIdx.x >> 4;
    const int h0    = h0i * 128;
    const int s0    = stile * 128;
    const int tid = threadIdx.x;
    const int wid = tid >> 6;
    const int lane = tid & 63;
    const int lr  = lane & 15;
    const int lk  = (lane >> 4) * 8;
    const int strow = tid >> 3;
    const int skc   = (tid & 7) * 8;

    f32x4 acc[2][8];
    {
        const unsigned short* hp = hpart
            + ((size_t)((b * 4 + h0i) * 4 + stile)) * 16384;
#pragma unroll
        for (int st = 0; st < 2; ++st)
#pragma unroll
            for (int ht = 0; ht < 8; ++ht) {
                const int f = (wid * 2 + st) * 8 + ht;
                const uint2 uu = *(const uint2*)(hp + f * 256 + lane * 4);
                acc[st][ht] = unpk(uu);
            }
    }

    auto stage = [&](int kstep, int buf) {
        const int k0 = kstep * KSTEP;
        const unsigned short* asrc;
        int koff, bcol;
        if (k0 < DD) { asrc = leftb;  koff = k0;      bcol = k0; }
        else         { asrc = rightb; koff = k0 - DD; bcol = k0 + 256; }
#pragma unroll
        for (int j = 0; j < 4; ++j) {
            const int row = strow + 32 * j;
            const int ss = s0 + row;
            *(bf16x8*)&Abuf[buf][row][skc] =
                *(const bf16x8*)(asrc + ((size_t)ss * BB + b) * DD + koff + skc);
            *(bf16x8*)&Bbuf[buf][row][skc] =
                *(const bf16x8*)(convwb + (size_t)(h0 + row) * K3D + bcol + skc);
        }
    };

    stage(0, 0);
    int cur = 0;
    for (int it = 0; it < NKC; ++it) {
        __syncthreads();
        if (it + 1 < NKC) stage(it + 1, cur ^ 1);

        const int wrow0 = wid * 32;
#pragma unroll
        for (int ks = 0; ks < 2; ++ks) {
            const int kk = ks * 32 + lk;
            const bf16x8 a0 = *(const bf16x8*)&Abuf[cur][wrow0 + lr][kk];
            const bf16x8 a1 = *(const bf16x8*)&Abuf[cur][wrow0 + 16 + lr][kk];
#pragma unroll
            for (int ht = 0; ht < 8; ++ht) {
                const bf16x8 bv = *(const bf16x8*)&Bbuf[cur][ht * 16 + lr][kk];
                acc[0][ht] = __builtin_amdgcn_mfma_f32_16x16x32_bf16(a0, bv, acc[0][ht], 0, 0, 0);
                acc[1][ht] = __builtin_amdgcn_mfma_f32_16x16x32_bf16(a1, bv, acc[1][ht], 0, 0, 0);
            }
        }
        cur ^= 1;
    }

    float pmax[8];
#pragma unroll
    for (int ht = 0; ht < 8; ++ht) {
        float m = -INFINITY;
#pragma unroll
        for (int st = 0; st < 2; ++st)
#pragma unroll
            for (int r = 0; r < 4; ++r)
                m = fmaxf(m, acc[st][ht][r]);
        m = fmaxf(m, __shfl_xor(m, 16));
        m = fmaxf(m, __shfl_xor(m, 32));
        if (lane < 16) red[wid][ht * 16 + lane] = m;
    }
    __syncthreads();
    if (tid < 128) {
        const float m = fmaxf(fmaxf(red[0][tid], red[1][tid]),
                              fmaxf(red[2][tid], red[3][tid]));
        const float v = fmaxf(m + conv_b[h0 + tid], 0.f);
        atomicMax((unsigned*)(pooled + (size_t)b * HH + h0 + tid),
                  __float_as_uint(v));
    }
}

// ---------------------------------------------------------------------------
// Kernel 4: final FC. 64 blocks (one per b), 320 threads: c = tid>>5,
// 32-lane group sums h-strided, shuffle-reduce within group.
// ---------------------------------------------------------------------------
__global__ __launch_bounds__(320) void fc_kernel(
    const float* __restrict__ pooled,
    const float* __restrict__ fc_w,
    const float* __restrict__ fc_b,
    float* __restrict__ out)
{
    const int b = blockIdx.x;
    const int c = threadIdx.x >> 5;
    const int l = threadIdx.x & 31;
    const float* pb = pooled + (size_t)b * HH;
    const float* wc = fc_w + (size_t)c * HH;
    float acc = 0.f;
#pragma unroll
    for (int i = 0; i < 16; ++i) {
        const int h = l + 32 * i;
        acc += pb[h] * wc[h];
    }
    acc += __shfl_xor(acc, 1);
    acc += __shfl_xor(acc, 2);
    acc += __shfl_xor(acc, 4);
    acc += __shfl_xor(acc, 8);
    acc += __shfl_xor(acc, 16);
    if (l == 0) out[b * NCLS + c] = acc + fc_b[c];
}

// ---------------------------------------------------------------------------
extern "C" void kernel_launch(void* const* d_in, const int* in_sizes, int n_in,
                              void* d_out, int out_size, void* d_ws, size_t ws_size,
                              hipStream_t stream)
{
    const int*   x       = (const int*)  d_in[0];
    const float* embed_w = (const float*)d_in[1];
    const float* Wl      = (const float*)d_in[2];
    const float* bl      = (const float*)d_in[3];
    const float* Wsl     = (const float*)d_in[4];
    const float* bsl     = (const float*)d_in[5];
    const float* Wr      = (const float*)d_in[6];
    const float* br      = (const float*)d_in[7];
    const float* Wsr     = (const float*)d_in[8];
    const float* bsr     = (const float*)d_in[9];
    const float* conv_w  = (const float*)d_in[10];
    const float* conv_b  = (const float*)d_in[11];
    const float* fc_w    = (const float*)d_in[12];
    const float* fc_b    = (const float*)d_in[13];
    const float* cl0     = (const float*)d_in[14];
    const float* cr0     = (const float*)d_in[15];
    float* out = (float*)d_out;

    char* ws = (char*)d_ws;
    const size_t SZh = (size_t)SS * BB * DD * sizeof(unsigned short);  // 16.78 MB
    unsigned short* pre2_l = (unsigned short*)(ws);
    unsigned short* pre2_r = (unsigned short*)(ws + SZh);
    unsigned short* leftb  = (unsigned short*)(ws + 2 * SZh);
    unsigned short* rightb = (unsigned short*)(ws + 3 * SZh);
    unsigned short* convwb = (unsigned short*)(ws + 4 * SZh);
    float*          pooled = (float*)(ws + 4 * SZh + (size_t)HH * K3D * 2);
    unsigned short* hpart  = (unsigned short*)(ws + 4 * SZh
                                               + (size_t)HH * K3D * 2
                                               + (size_t)BB * HH * 4);

    prep_pre_kernel<<<1217, 256, 0, stream>>>(
        Wsl, Wsr, bsl, bl, bsr, br, x, embed_w, conv_w,
        convwb, pre2_l, pre2_r, pooled);

    recur_conve_kernel<<<136, 256, 0, stream>>>(
        Wl, Wr, cl0, cr0, pre2_l, pre2_r, leftb, rightb,
        x, embed_w, convwb, hpart);

    conv_pool_kernel<<<1024, 256, 0, stream>>>(
        leftb, rightb, convwb, hpart, conv_b, pooled);

    fc_kernel<<<BB, 320, 0, stream>>>(pooled, fc_w, fc_b, out);
}